// Round 2
// baseline (220.955 us; speedup 1.0000x reference)
//
#include <hip/hip_runtime.h>

// out[n,c,h,w]:
//   c in [0,64)    : x[n, c+64, (h-1)&63, w]
//   c in [64,128)  : x[n, c-64, (h+1)&63, w]
//   c in [128,192) : x[n, c+64, h, (w-1)&63]
//   c in [192,256) : x[n, c-64, h, (w+1)&63]
//
// Layout: N=32, C=256, H=64, W=64. One thread per 8 floats (2x vec4) of output.
// tid bits: [0:2]=w8, [3:8]=h, [9:16]=c, [17:]=n.  out flat float index == 8*tid.
// g = c>>6 is block-uniform (c constant per block), so no divergence.
// w-shift groups (g=2,3) get the wrap element from the neighboring lane via
// __shfl within the 8-lane row group instead of a second global load.
// Non-temporal loads/stores: both streams are touch-once (no reuse to cache).
// NOTE: __builtin_nontemporal_* requires a NATIVE vector type, not HIP float4.

typedef float vf4 __attribute__((ext_vector_type(4)));

__global__ __launch_bounds__(256) void swap_kernel(const float* __restrict__ x,
                                                   float* __restrict__ out) {
    const int tid = blockIdx.x * blockDim.x + threadIdx.x;
    const int w0 = (tid & 7) << 3;         // 0,8,...,56
    const int h  = (tid >> 3) & 63;
    const int c  = (tid >> 9) & 255;
    const int n  = tid >> 17;
    const int g  = c >> 6;                 // block-uniform
    const int l  = threadIdx.x & 7;        // lane position within 8-lane row group

    const int nbase = n << 20;             // n * 256 * 4096 (floats)
    vf4 r0, r1;

    if (g < 2) {
        // pure row-shifted copy, stays vec4-aligned
        const int src_c = (g == 0) ? (c + 64) : (c - 64);
        const int src_h = (g == 0) ? ((h - 1) & 63) : ((h + 1) & 63);
        const vf4* src = reinterpret_cast<const vf4*>(
            x + nbase + (src_c << 12) + (src_h << 6) + w0);
        r0 = __builtin_nontemporal_load(src);
        r1 = __builtin_nontemporal_load(src + 1);
    } else if (g == 2) {
        // out[w] = row[(w-1)&63]
        const vf4* src = reinterpret_cast<const vf4*>(
            x + nbase + ((c + 64) << 12) + (h << 6) + w0);
        vf4 f0 = __builtin_nontemporal_load(src);
        vf4 f1 = __builtin_nontemporal_load(src + 1);
        float prv = __shfl(f1.w, (l - 1) & 7, 8);   // row[(w0-1)&63] from prev lane
        r0 = (vf4){prv,  f0.x, f0.y, f0.z};
        r1 = (vf4){f0.w, f1.x, f1.y, f1.z};
    } else {
        // out[w] = row[(w+1)&63]
        const vf4* src = reinterpret_cast<const vf4*>(
            x + nbase + ((c - 64) << 12) + (h << 6) + w0);
        vf4 f0 = __builtin_nontemporal_load(src);
        vf4 f1 = __builtin_nontemporal_load(src + 1);
        float nx = __shfl(f0.x, (l + 1) & 7, 8);    // row[(w0+8)&63] from next lane
        r0 = (vf4){f0.y, f0.z, f0.w, f1.x};
        r1 = (vf4){f1.y, f1.z, f1.w, nx};
    }

    vf4* dst = reinterpret_cast<vf4*>(out + ((long)tid << 3));
    __builtin_nontemporal_store(r0, dst);
    __builtin_nontemporal_store(r1, dst + 1);
}

extern "C" void kernel_launch(void* const* d_in, const int* in_sizes, int n_in,
                              void* d_out, int out_size, void* d_ws, size_t ws_size,
                              hipStream_t stream) {
    const float* x   = (const float*)d_in[0];
    float*       out = (float*)d_out;
    // total 8-float chunks = 32*256*64*8 = 4,194,304 -> 16384 blocks of 256
    const int total_vec8 = (32 * 256 * 64 * 64) / 8;
    const int block = 256;
    const int grid  = total_vec8 / block;  // 16384
    swap_kernel<<<grid, block, 0, stream>>>(x, out);
}